// Round 17
// baseline (122.882 us; speedup 1.0000x reference)
//
#include <hip/hip_runtime.h>
#include <math.h>

#define N 8192
#define H 128
#define NEV 64
#define SS 20
#define MAXD 512
#define MAXDIRTY 128
#define RPB 32
#define SPIN_GUARD (1 << 18)

// ---------------------------------------------------------------------------
// k_embz: z_out = emb copy ; d0/d1 rate dots. (r16 k_emb minus the h-matvec —
// h_tab is now computed inline in k_nbrdm for just the rows Mstat needs.)
// ---------------------------------------------------------------------------
__global__ __launch_bounds__(512) void k_embz(
    const float* __restrict__ emb, const float* __restrict__ W_om,
    float* __restrict__ z_out, float* __restrict__ d0, float* __restrict__ d1)
{
    const int tid = threadIdx.x;
    const int r0 = blockIdx.x * RPB;

    __shared__ __align__(16) float z4[4 * 128];

    const int lane = tid & 63;
    const int wid = tid >> 6;
    const int kof = (wid >= 4) ? 256 : 0;
    const float wk_l = W_om[kof + lane]      + W_om[kof + 128 + lane];
    const float wk_h = W_om[kof + 64 + lane] + W_om[kof + 192 + lane];

    for (int b = 0; b < RPB / 4; ++b) {
        const int rbase = r0 + b * 4;
        __syncthreads();
        const float zv = emb[(size_t)rbase * H + tid];
        z4[tid] = zv;
        z_out[(size_t)rbase * H + tid] = zv;
        __syncthreads();
        {
            const int rr = wid & 3;
            float val = z4[rr * 128 + lane] * wk_l + z4[rr * 128 + 64 + lane] * wk_h;
#pragma unroll
            for (int off = 32; off > 0; off >>= 1) val += __shfl_xor(val, off);
            if (lane == 0) {
                if (wid < 4) d0[rbase + rr] = val;
                else         d1[rbase + rr] = val;
            }
        }
    }
}

// ---------------------------------------------------------------------------
// k_nbrdm: neighbor-compaction + INLINE-h Mstat + dirty-list, one block per
// slot, all lists in LDS. NEW vs r16: h_j = W_h.emb[j] + b_h computed on the
// fly (W_h row in VGPRs, emb row staged in LDS) — no h_tab dependence.
// ---------------------------------------------------------------------------
__global__ __launch_bounds__(256) void k_nbrdm(
    const int* __restrict__ u, const int* __restrict__ v,
    const float* __restrict__ A, const float* __restrict__ S,
    const float* __restrict__ emb,
    const float* __restrict__ W_h, const float* __restrict__ b_h,
    int* __restrict__ deg, float* __restrict__ Mstat,
    int* __restrict__ dcnt, int* __restrict__ dl_s, float* __restrict__ dl_q,
    unsigned long long* __restrict__ donebits)
{
    __shared__ float rs[256];
    __shared__ int   nbrL_i[MAXD];
    __shared__ float nbrL_e[MAXD];
    __shared__ int   flagL[MAXD];
    __shared__ float redm[256];
    __shared__ int   nodL[2 * NEV];
    __shared__ int   dlL_s[MAXDIRTY];
    __shared__ float dlL_q[MAXDIRTY];
    __shared__ __align__(16) float erow[2][128];
    __shared__ int   cntL, dcL;
    __shared__ float sumL;

    const int slot = blockIdx.x;
    const int e = slot >> 1, side = slot & 1;
    const int row = (side == 0) ? v[e] : u[e];
    const size_t base = (size_t)row * N;
    const int tid = threadIdx.x;

    if (blockIdx.x == 0 && tid == 0) donebits[0] = 0ull;   // for k_parls (next dispatch)
    if (tid == 0) { cntL = 0; dcL = 0; }
    if (tid < 2 * NEV) nodL[tid] = (tid & 1) ? u[tid >> 1] : v[tid >> 1];
    __syncthreads();

    // ---- phase 1: scan adjacency row, compact into LDS, sum exp(S) ----
    float lsum = 0.f;
    for (int j = tid; j < N; j += 256) {
        if (A[base + j] > 0.f) {
            const float ev = expf(S[base + j]);
            lsum += ev;
            const int p = atomicAdd(&cntL, 1);
            if (p < MAXD) { nbrL_i[p] = j; nbrL_e[p] = ev; }
        }
    }
    rs[tid] = lsum;
    __syncthreads();
    for (int off = 128; off > 0; off >>= 1) {
        if (tid < off) rs[tid] += rs[tid + off];
        __syncthreads();
    }
    if (tid == 0) { sumL = rs[0]; deg[slot] = cntL; }
    __syncthreads();

    const int d = min(cntL, MAXD);
    const float rinv = 1.f / (sumL + 1e-7f);

    // ---- phase 1.5: per-neighbor latest-updater slot strictly before e ----
    for (int j0 = tid; j0 < d; j0 += 256) {
        const int j = nbrL_i[j0];
        int dep = -1;
        for (int s2 = 2 * e - 1; s2 >= 0; --s2)
            if (nodL[s2] == j) { dep = s2; break; }
        flagL[j0] = dep;                      // <0: static; >=0: dirty dep slot
    }
    __syncthreads();

    // ---- phase 2: Mstat over static neighbors, h computed inline ----
    {
        const int c = tid & 127, half = tid >> 7;
        float4 wh[32];
#pragma unroll
        for (int i = 0; i < 32; ++i)
            wh[i] = ((const float4*)(W_h + (size_t)c * H))[i];
        const float bh_c = b_h[c];

        float m = -INFINITY;
        const int nIter = (d + 1) >> 1;
        for (int it = 0; it < nIter; ++it) {
            const int j0 = 2 * it + half;     // this half's neighbor index
            const bool valid = (j0 < d);
            __syncthreads();                  // protect erow reuse
            if (valid) erow[half][c] = emb[(size_t)nbrL_i[j0] * H + c];
            __syncthreads();
            if (valid && flagL[j0] < 0) {
                float h = bh_c;
#pragma unroll
                for (int i = 0; i < 32; ++i) {
                    const float4 ez = *(const float4*)&erow[half][4 * i];
                    h += ez.x * wh[i].x + ez.y * wh[i].y +
                         ez.z * wh[i].z + ez.w * wh[i].w;
                }
                m = fmaxf(m, nbrL_e[j0] * rinv * h);
            }
        }
        redm[tid] = m;
        __syncthreads();
        if (tid < 128) Mstat[slot * H + c] = fmaxf(redm[c], redm[128 + c]);
    }

    // ---- phase 3: dirty list (latest-updater dep slots) ----
    for (int j0 = tid; j0 < d; j0 += 256) {
        const int dep = flagL[j0];
        if (dep >= 0) {
            const int p = atomicAdd(&dcL, 1);
            if (p < MAXDIRTY) { dlL_s[p] = dep; dlL_q[p] = nbrL_e[j0] * rinv; }
        }
    }
    __syncthreads();
    if (tid == 0) dcnt[slot] = dcL;
    const int nd = min(dcL, MAXDIRTY);
    for (int p = tid; p < nd; p += 256) {
        dl_s[slot * MAXDIRTY + p] = dlL_s[p];
        dl_q[slot * MAXDIRTY + p] = dlL_q[p];
    }
}

// ---------------------------------------------------------------------------
// k_parls: blocks 0..63 = par role; block 64 = lam; 65..84 = survival.
// [byte-identical to round 16 — passed]
// ---------------------------------------------------------------------------
__global__ __launch_bounds__(256) void k_parls(
    const int* __restrict__ u, const int* __restrict__ v,
    const float* __restrict__ t, const int* __restrict__ kk,
    const int* __restrict__ u_o, const int* __restrict__ v_o,
    const float* __restrict__ lastt, const float* __restrict__ emb,
    const float* __restrict__ W_S, const float* __restrict__ W_R,
    const float* __restrict__ W_t, const float* __restrict__ W_h,
    const float* __restrict__ b_h,
    const float* __restrict__ psi, const float* __restrict__ b_om,
    const float* __restrict__ d0, const float* __restrict__ d1,
    const int* __restrict__ deg, const int* __restrict__ dcnt,
    const int* __restrict__ dl_s, const float* __restrict__ dl_q,
    const float* __restrict__ Mstat,
    float* __restrict__ z_slot, float* __restrict__ h_slot,
    unsigned long long* __restrict__ donebits,
    float* __restrict__ lamout, float* __restrict__ svout,
    float* __restrict__ z_out)
{
    const int bid = blockIdx.x;
    const int tid = threadIdx.x;

    if (bid >= NEV) {
        // ================= lam / survival roles (prior-dispatch reads only) ====
        if (bid == NEV) {
            if (tid < NEV) {
                const int b = tid;
                const int kv = kk[b];
                const float* dk = kv ? d1 : d0;
                const float g = 0.5f * (dk[u[b]] + dk[v[b]]) + b_om[kv];
                const float ps = psi[kv];
                const float x = fminf(75.f, fmaxf(-75.f, g / ps));
                lamout[b] = ps * log1pf(expf(x));
            }
        } else {
            const int s = bid - NEV - 1;
            if (tid < 64) {
                const int b = tid;
                const float p0 = psi[0], p1 = psi[1], bo0 = b_om[0], bo1 = b_om[1];
                const int vo = v_o[b * SS + s], uo = u_o[b * SS + s];
                float g, x;
                g = 0.5f * (d0[u[b]] + d0[vo]) + bo0; x = fminf(75.f, fmaxf(-75.f, g / p0));
                const float ru0 = p0 * log1pf(expf(x));
                g = 0.5f * (d1[u[b]] + d1[vo]) + bo1; x = fminf(75.f, fmaxf(-75.f, g / p1));
                const float ru1 = p1 * log1pf(expf(x));
                g = 0.5f * (d1[v[b]] + d1[uo]) + bo1; x = fminf(75.f, fmaxf(-75.f, g / p1));
                const float rv1 = p1 * log1pf(expf(x));
                float val = 2.f * (ru0 + ru1) + rv1;
#pragma unroll
                for (int off = 32; off > 0; off >>= 1) val += __shfl_xor(val, off);
                if (b == 0) svout[s] = val / (float)SS;
            }
        }
        return;
    }

    // ================= par role (verbatim rounds 15/16) ====================
    const int e = bid;
    const int r = tid >> 7;             // wave-uniform (waves 0-1: r=0, 2-3: r=1)
    const int c = tid & 127;
    const int slot = 2 * e + r;

    __shared__ __align__(16) float hs_s[2][128];
    __shared__ __align__(16) float zz_s[2][128];
    __shared__ __align__(16) float zn_s[2][128];
    __shared__ int   uL[NEV], vL[NEV];
    __shared__ int   zdepL[2], lastupL[2], nodeL[2];
    __shared__ float dtvL[2];
    __shared__ unsigned long long need_s;

    if (tid < NEV)                 uL[tid] = u[tid];
    else if (tid < 2 * NEV)        vL[tid - NEV] = v[tid - NEV];
    __syncthreads();

    // ---- per-slot metadata from the event list ----
    if (tid < 2) {
        const int sl = 2 * e + tid;
        const int node = tid ? uL[e] : vL[e];    // slot 2e -> v[e], 2e+1 -> u[e]
        nodeL[tid] = node;
        int zd = -1;
        for (int j = 2 * e - 1; j >= 0; --j) {
            const int nj = (j & 1) ? uL[j >> 1] : vL[j >> 1];
            if (nj == node) { zd = j; break; }
        }
        zdepL[tid] = zd;
        int lu = 1;
        for (int j = sl + 1; j < 2 * NEV; ++j) {
            const int nj = (j & 1) ? uL[j >> 1] : vL[j >> 1];
            if (nj == node) { lu = 0; break; }
        }
        lastupL[tid] = lu;
        const int dtn = tid ? vL[e] : uL[e];     // crossed: row v uses let[u], row u let[v]
        int pt = -1;
        for (int e2 = e - 1; e2 >= 0; --e2)
            if (uL[e2] == dtn || vL[e2] == dtn) { pt = e2; break; }
        const float lv = (pt >= 0) ? t[pt] : lastt[dtn];
        dtvL[tid] = t[e] - lv;
    }
    __syncthreads();

    // ---- build need-mask and spin (thread 0), then per-thread acquire ----
    if (tid == 0) {
        unsigned long long need = 0ull;
        for (int rr = 0; rr < 2; ++rr) {
            const int zd = zdepL[rr];
            if (zd >= 0) need |= 1ull << (zd >> 1);
            const int sl = 2 * e + rr;
            const int dn = min(dcnt[sl], MAXDIRTY);
            for (int p = 0; p < dn; ++p)
                need |= 1ull << (dl_s[sl * MAXDIRTY + p] >> 1);
        }
        need_s = need;
        if (need) {
            int guard = 0;
            while ((__hip_atomic_load(donebits, __ATOMIC_ACQUIRE,
                                      __HIP_MEMORY_SCOPE_AGENT) & need) != need) {
                __builtin_amdgcn_s_sleep(2);
                if (++guard > SPIN_GUARD) break;       // safety valve
            }
        }
    }
    __syncthreads();
    if (need_s) {   // per-thread acquire: invalidate stale cache lines on this CU
        unsigned long long db = __hip_atomic_load(donebits, __ATOMIC_ACQUIRE,
                                                  __HIP_MEMORY_SCOPE_AGENT);
        (void)db;
    }

    // ---- Phase A: hs (Mstat static max + dirty via h_slot) and z (versioned) ----
    {
        float m = Mstat[slot * H + c];
        const int dn = min(dcnt[slot], MAXDIRTY);
        for (int p = 0; p < dn; ++p) {
            const int ds = dl_s[slot * MAXDIRTY + p];
            const float q = dl_q[slot * MAXDIRTY + p];
            m = fmaxf(m, q * h_slot[ds * H + c]);
        }
        hs_s[r][c] = (deg[slot] > 0) ? 1.f / (1.f + __expf(-m)) : 0.f;
        const int zd = zdepL[r];
        zz_s[r][c] = (zd >= 0) ? z_slot[zd * H + c]
                               : emb[(size_t)nodeL[r] * H + c];
    }
    __syncthreads();

    // ---- Phase B: g = hs.W_S[c] + z.W_R[c] + dt*W_t[c]; sigmoid ----
    float g = 0.f;
    {
        const float4* ws4 = (const float4*)(W_S + (size_t)c * H);
        const float4* wr4 = (const float4*)(W_R + (size_t)c * H);
#pragma unroll
        for (int i = 0; i < 32; ++i) {
            const float4 a = ws4[i];
            const float4 b = wr4[i];
            const float4 hh = *(const float4*)&hs_s[r][4 * i];   // LDS broadcast
            const float4 zz = *(const float4*)&zz_s[r][4 * i];
            g += hh.x * a.x + hh.y * a.y + hh.z * a.z + hh.w * a.w +
                 zz.x * b.x + zz.y * b.y + zz.z * b.z + zz.w * b.w;
        }
    }
    g += dtvL[r] * W_t[c];
    const float zv = 1.f / (1.f + __expf(-g));
    zn_s[r][c] = zv;
    z_slot[slot * H + c] = zv;                      // versioned publish (z)
    if (lastupL[r])                                 // final updater writes output
        z_out[(size_t)nodeL[r] * H + c] = zv;
    __syncthreads();                                // zn_s ready for phase C

    // ---- Phase C: publish h_slot[slot] (unconditional) ----
    {
        float h = 0.f;
        const float4* wh4 = (const float4*)(W_h + (size_t)c * H);
#pragma unroll
        for (int i = 0; i < 32; ++i) {
            const float4 a = wh4[i];
            const float4 zz = *(const float4*)&zn_s[r][4 * i];
            h += zz.x * a.x + zz.y * a.y + zz.z * a.z + zz.w * a.w;
        }
        h_slot[slot * H + c] = h + b_h[c];
    }

    // ---- release (unconditional) ----
    __syncthreads();
    if (tid == 0) {
        __threadfence();                            // agent-scope write visibility
        __hip_atomic_fetch_or(donebits, 1ull << e, __ATOMIC_RELEASE,
                              __HIP_MEMORY_SCOPE_AGENT);
    }
}

// ---------------------------------------------------------------------------
extern "C" void kernel_launch(void* const* d_in, const int* in_sizes, int n_in,
                              void* d_out, int out_size, void* d_ws, size_t ws_size,
                              hipStream_t stream)
{
    const int*   u        = (const int*)d_in[0];
    const int*   v        = (const int*)d_in[1];
    const float* t        = (const float*)d_in[2];
    const int*   k        = (const int*)d_in[3];
    const int*   u_others = (const int*)d_in[4];
    const int*   v_others = (const int*)d_in[5];
    const float* A        = (const float*)d_in[6];
    const float* S        = (const float*)d_in[7];
    const float* emb      = (const float*)d_in[8];
    const float* lastt    = (const float*)d_in[9];
    const float* W_S      = (const float*)d_in[10];
    const float* W_R      = (const float*)d_in[11];
    const float* W_t      = (const float*)d_in[12];
    const float* W_h      = (const float*)d_in[13];
    const float* b_h      = (const float*)d_in[14];
    const float* psi      = (const float*)d_in[15];
    const float* W_om     = (const float*)d_in[16];
    const float* b_om     = (const float*)d_in[17];
    (void)in_sizes; (void)n_in; (void)out_size; (void)ws_size;

    // Workspace layout byte-identical to round 16 (h_tab slot now unused —
    // kept to avoid layout-change risk).
    float* wsf    = (float*)d_ws;
    float* h_tab  = wsf;                            // N*H (dead)
    float* d0     = h_tab + (size_t)N * H;          // N
    float* d1     = d0 + N;                         // N
    float* Mstat  = d1 + N;                         // 128*H
    float* dl_q   = Mstat + 128 * H;                // 128*MAXDIRTY
    float* z_slot = dl_q + 128 * MAXDIRTY;          // 128*H
    float* h_slot = z_slot + 128 * H;               // 128*H
    int*   deg    = (int*)(h_slot + 128 * H);       // 128
    int*   dcnt   = deg + 128;                      // 128
    int*   dl_s   = dcnt + 128;                     // 128*MAXDIRTY
    unsigned long long* donebits = (unsigned long long*)(dl_s + 128 * MAXDIRTY);

    float* out    = (float*)d_out;
    float* lamout = out;            // [64]
    float* svout  = out + NEV;      // [20]
    float* z_out  = out + NEV + SS; // [N*H]

    k_embz<<<N / RPB, 512, 0, stream>>>(emb, W_om, z_out, d0, d1);
    k_nbrdm<<<128, 256, 0, stream>>>(u, v, A, S, emb, W_h, b_h,
                                     deg, Mstat, dcnt, dl_s, dl_q, donebits);
    k_parls<<<NEV + 1 + SS, 256, 0, stream>>>(u, v, t, k, u_others, v_others,
                                              lastt, emb, W_S, W_R, W_t, W_h, b_h,
                                              psi, b_om, d0, d1,
                                              deg, dcnt, dl_s, dl_q, Mstat,
                                              z_slot, h_slot, donebits,
                                              lamout, svout, z_out);
}

// Round 18
// 110.127 us; speedup vs baseline: 1.1158x; 1.1158x over previous
//
#include <hip/hip_runtime.h>
#include <math.h>

#define N 8192
#define H 128
#define NEV 64
#define SS 20
#define MAXD 512
#define MAXDIRTY 128
#define RPB 32
#define SPIN_GUARD (1 << 18)

// ---------------------------------------------------------------------------
// k_emb: h_tab = emb @ W_h.T + b_h ; z_out = emb copy ; d0/d1 rate dots.
// [r16 version (6x passed) + one line: block 0 zeroes donebits for the next
// dispatch]
// ---------------------------------------------------------------------------
__global__ __launch_bounds__(512) void k_emb(
    const float* __restrict__ emb, const float* __restrict__ W_h,
    const float* __restrict__ b_h, const float* __restrict__ W_om,
    float* __restrict__ h_tab, float* __restrict__ z_out,
    float* __restrict__ d0, float* __restrict__ d1,
    unsigned long long* __restrict__ donebits)
{
    const int tid = threadIdx.x;
    const int c = tid & 127;
    const int s = tid >> 7;             // 0..3
    const int r0 = blockIdx.x * RPB;

    if (blockIdx.x == 0 && tid == 0) donebits[0] = 0ull;   // for k_parls

    __shared__ __align__(16) float z4[4 * 128];
    __shared__ float pr[8 * 128];

    float whr[32];
#pragma unroll
    for (int i = 0; i < 32; ++i) whr[i] = W_h[c * H + s * 32 + i];
    const float bh_c = b_h[c];

    const int lane = tid & 63;
    const int wid = tid >> 6;
    const int kof = (wid >= 4) ? 256 : 0;
    const float wk_l = W_om[kof + lane]      + W_om[kof + 128 + lane];
    const float wk_h = W_om[kof + 64 + lane] + W_om[kof + 192 + lane];

    for (int b = 0; b < RPB / 4; ++b) {
        const int rbase = r0 + b * 4;
        __syncthreads();
        const float zv = emb[(size_t)rbase * H + tid];
        z4[tid] = zv;
        z_out[(size_t)rbase * H + tid] = zv;
        __syncthreads();

#pragma unroll
        for (int rr = 0; rr < 4; ++rr) {
            float a = 0.f;
#pragma unroll
            for (int i4 = 0; i4 < 8; ++i4) {
                const float4 zz = *(const float4*)&z4[rr * 128 + s * 32 + i4 * 4];
                a += zz.x * whr[i4 * 4] + zz.y * whr[i4 * 4 + 1] +
                     zz.z * whr[i4 * 4 + 2] + zz.w * whr[i4 * 4 + 3];
            }
            pr[(s * 4 + rr) * 128 + c] = a;
        }
        {
            const int rr = wid & 3;
            float val = z4[rr * 128 + lane] * wk_l + z4[rr * 128 + 64 + lane] * wk_h;
#pragma unroll
            for (int off = 32; off > 0; off >>= 1) val += __shfl_xor(val, off);
            if (lane == 0) {
                if (wid < 4) d0[rbase + rr] = val;
                else         d1[rbase + rr] = val;
            }
        }
        __syncthreads();
        {
            const int rr = s;
            const float h = pr[(0 * 4 + rr) * 128 + c] + pr[(1 * 4 + rr) * 128 + c] +
                            pr[(2 * 4 + rr) * 128 + c] + pr[(3 * 4 + rr) * 128 + c] + bh_c;
            h_tab[(size_t)(rbase + rr) * H + c] = h;
        }
    }
}

// ---------------------------------------------------------------------------
// k_parls: blocks 0..63 = par role WITH INLINE PREP (r16 k_nbrdm logic run
// for the block's own 2 slots, results in LDS — no global Mstat/dl/deg);
// block 64 = lam; 65..84 = survival (verbatim r16, prior-dispatch reads).
// Cross-block communication remains ONLY the r9-proven donebits protocol.
// ---------------------------------------------------------------------------
__global__ __launch_bounds__(256) void k_parls(
    const int* __restrict__ u, const int* __restrict__ v,
    const float* __restrict__ t, const int* __restrict__ kk,
    const int* __restrict__ u_o, const int* __restrict__ v_o,
    const float* __restrict__ lastt, const float* __restrict__ emb,
    const float* __restrict__ A, const float* __restrict__ S,
    const float* __restrict__ h_tab,
    const float* __restrict__ W_S, const float* __restrict__ W_R,
    const float* __restrict__ W_t, const float* __restrict__ W_h,
    const float* __restrict__ b_h,
    const float* __restrict__ psi, const float* __restrict__ b_om,
    const float* __restrict__ d0, const float* __restrict__ d1,
    float* __restrict__ z_slot, float* __restrict__ h_slot,
    unsigned long long* __restrict__ donebits,
    float* __restrict__ lamout, float* __restrict__ svout,
    float* __restrict__ z_out)
{
    const int bid = blockIdx.x;
    const int tid = threadIdx.x;

    if (bid >= NEV) {
        // ========== lam / survival roles (prior-dispatch reads only) =======
        if (bid == NEV) {
            if (tid < NEV) {
                const int b = tid;
                const int kv = kk[b];
                const float* dk = kv ? d1 : d0;
                const float g = 0.5f * (dk[u[b]] + dk[v[b]]) + b_om[kv];
                const float ps = psi[kv];
                const float x = fminf(75.f, fmaxf(-75.f, g / ps));
                lamout[b] = ps * log1pf(expf(x));
            }
        } else {
            const int s = bid - NEV - 1;
            if (tid < 64) {
                const int b = tid;
                const float p0 = psi[0], p1 = psi[1], bo0 = b_om[0], bo1 = b_om[1];
                const int vo = v_o[b * SS + s], uo = u_o[b * SS + s];
                float g, x;
                g = 0.5f * (d0[u[b]] + d0[vo]) + bo0; x = fminf(75.f, fmaxf(-75.f, g / p0));
                const float ru0 = p0 * log1pf(expf(x));
                g = 0.5f * (d1[u[b]] + d1[vo]) + bo1; x = fminf(75.f, fmaxf(-75.f, g / p1));
                const float ru1 = p1 * log1pf(expf(x));
                g = 0.5f * (d1[v[b]] + d1[uo]) + bo1; x = fminf(75.f, fmaxf(-75.f, g / p1));
                const float rv1 = p1 * log1pf(expf(x));
                float val = 2.f * (ru0 + ru1) + rv1;
#pragma unroll
                for (int off = 32; off > 0; off >>= 1) val += __shfl_xor(val, off);
                if (b == 0) svout[s] = val / (float)SS;
            }
        }
        return;
    }

    // ==================== par role with inline prep ========================
    const int e = bid;
    const int r = tid >> 7;             // wave-uniform: 0 = v-row, 1 = u-row
    const int c = tid & 127;
    const int slot = 2 * e + r;

    __shared__ int   uL[NEV], vL[NEV];
    __shared__ int   nbr_i[MAXD];
    __shared__ float nbr_e[MAXD];
    __shared__ int   flagL[MAXD];
    __shared__ float rs[256];
    __shared__ float redm[256];
    __shared__ float msA[2][128];
    __shared__ int   dlsA[2][MAXDIRTY];
    __shared__ float dlqA[2][MAXDIRTY];
    __shared__ int   dcA[2], degA[2];
    __shared__ int   cntL, dcL;
    __shared__ float sumL;
    __shared__ __align__(16) float hs_s[2][128];
    __shared__ __align__(16) float zz_s[2][128];
    __shared__ __align__(16) float zn_s[2][128];
    __shared__ int   zdepL[2], lastupL[2], nodeL[2];
    __shared__ float dtvL[2];
    __shared__ unsigned long long need_s;

    if (tid < NEV)          uL[tid] = u[tid];
    else if (tid < 2 * NEV) vL[tid - NEV] = v[tid - NEV];
    __syncthreads();

    // ---- per-slot metadata from the event list (verbatim r16) ----
    if (tid < 2) {
        const int sl = 2 * e + tid;
        const int node = tid ? uL[e] : vL[e];    // slot 2e -> v[e], 2e+1 -> u[e]
        nodeL[tid] = node;
        int zd = -1;
        for (int j = 2 * e - 1; j >= 0; --j) {
            const int nj = (j & 1) ? uL[j >> 1] : vL[j >> 1];
            if (nj == node) { zd = j; break; }
        }
        zdepL[tid] = zd;
        int lu = 1;
        for (int j = sl + 1; j < 2 * NEV; ++j) {
            const int nj = (j & 1) ? uL[j >> 1] : vL[j >> 1];
            if (nj == node) { lu = 0; break; }
        }
        lastupL[tid] = lu;
        const int dtn = tid ? vL[e] : uL[e];     // crossed dt
        int pt = -1;
        for (int e2 = e - 1; e2 >= 0; --e2)
            if (uL[e2] == dtn || vL[e2] == dtn) { pt = e2; break; }
        const float lv = (pt >= 0) ? t[pt] : lastt[dtn];
        dtvL[tid] = t[e] - lv;
    }
    __syncthreads();

    // ---- inline prep: r16 k_nbrdm logic for this block's 2 slots ----
    for (int sl = 0; sl < 2; ++sl) {
        const int row = sl ? uL[e] : vL[e];
        const size_t base = (size_t)row * N;
        if (tid == 0) { cntL = 0; dcL = 0; }
        __syncthreads();

        // phase 1: scan adjacency row, compact into LDS, sum exp(S)
        float lsum = 0.f;
        for (int j = tid; j < N; j += 256) {
            if (A[base + j] > 0.f) {
                const float ev = expf(S[base + j]);
                lsum += ev;
                const int p = atomicAdd(&cntL, 1);
                if (p < MAXD) { nbr_i[p] = j; nbr_e[p] = ev; }
            }
        }
        rs[tid] = lsum;
        __syncthreads();
        for (int off = 128; off > 0; off >>= 1) {
            if (tid < off) rs[tid] += rs[tid + off];
            __syncthreads();
        }
        if (tid == 0) { sumL = rs[0]; degA[sl] = cntL; }
        __syncthreads();

        const int d = min(cntL, MAXD);
        const float rinv = 1.f / (sumL + 1e-7f);

        // phase 1.5: per-neighbor latest-updater slot strictly before e
        for (int j0 = tid; j0 < d; j0 += 256) {
            const int j = nbr_i[j0];
            int dep = -1;
            for (int s2 = 2 * e - 1; s2 >= 0; --s2) {
                const int nj = (s2 & 1) ? uL[s2 >> 1] : vL[s2 >> 1];
                if (nj == j) { dep = s2; break; }
            }
            flagL[j0] = dep;                  // <0: static; >=0: dirty dep slot
        }
        __syncthreads();

        // phase 2: Mstat over static neighbors (h from h_tab, prior dispatch)
        {
            const int cc = tid & 127, half = tid >> 7;
            float m = -INFINITY;
            for (int j0 = half; j0 < d; j0 += 2) {
                if (flagL[j0] < 0)
                    m = fmaxf(m, nbr_e[j0] * rinv * h_tab[(size_t)nbr_i[j0] * H + cc]);
            }
            redm[tid] = m;
            __syncthreads();
            if (tid < 128) msA[sl][cc] = fmaxf(redm[cc], redm[128 + cc]);
        }

        // phase 3: dirty list (latest-updater dep slots)
        for (int j0 = tid; j0 < d; j0 += 256) {
            const int dep = flagL[j0];
            if (dep >= 0) {
                const int p = atomicAdd(&dcL, 1);
                if (p < MAXDIRTY) { dlsA[sl][p] = dep; dlqA[sl][p] = nbr_e[j0] * rinv; }
            }
        }
        __syncthreads();
        if (tid == 0) dcA[sl] = dcL;
        __syncthreads();                      // nbr_i/e/flag reused next iter
    }

    // ---- build need-mask and spin (thread 0), then per-thread acquire ----
    if (tid == 0) {
        unsigned long long need = 0ull;
        for (int rr = 0; rr < 2; ++rr) {
            const int zd = zdepL[rr];
            if (zd >= 0) need |= 1ull << (zd >> 1);
            const int dn = min(dcA[rr], MAXDIRTY);
            for (int p = 0; p < dn; ++p)
                need |= 1ull << (dlsA[rr][p] >> 1);
        }
        need_s = need;
        if (need) {
            int guard = 0;
            while ((__hip_atomic_load(donebits, __ATOMIC_ACQUIRE,
                                      __HIP_MEMORY_SCOPE_AGENT) & need) != need) {
                __builtin_amdgcn_s_sleep(2);
                if (++guard > SPIN_GUARD) break;       // safety valve
            }
        }
    }
    __syncthreads();
    if (need_s) {   // per-thread acquire: invalidate stale cache lines on this CU
        unsigned long long db = __hip_atomic_load(donebits, __ATOMIC_ACQUIRE,
                                                  __HIP_MEMORY_SCOPE_AGENT);
        (void)db;
    }

    // ---- Phase A: hs (Mstat + dirty via h_slot) and z (versioned) ----
    {
        float m = msA[r][c];
        const int dn = min(dcA[r], MAXDIRTY);
        for (int p = 0; p < dn; ++p) {
            const int ds = dlsA[r][p];
            const float q = dlqA[r][p];
            m = fmaxf(m, q * h_slot[ds * H + c]);
        }
        hs_s[r][c] = (degA[r] > 0) ? 1.f / (1.f + __expf(-m)) : 0.f;
        const int zd = zdepL[r];
        zz_s[r][c] = (zd >= 0) ? z_slot[zd * H + c]
                               : emb[(size_t)nodeL[r] * H + c];
    }
    __syncthreads();

    // ---- Phase B: g = hs.W_S[c] + z.W_R[c] + dt*W_t[c]; sigmoid ----
    float g = 0.f;
    {
        const float4* ws4 = (const float4*)(W_S + (size_t)c * H);
        const float4* wr4 = (const float4*)(W_R + (size_t)c * H);
#pragma unroll
        for (int i = 0; i < 32; ++i) {
            const float4 a = ws4[i];
            const float4 b = wr4[i];
            const float4 hh = *(const float4*)&hs_s[r][4 * i];   // LDS broadcast
            const float4 zz = *(const float4*)&zz_s[r][4 * i];
            g += hh.x * a.x + hh.y * a.y + hh.z * a.z + hh.w * a.w +
                 zz.x * b.x + zz.y * b.y + zz.z * b.z + zz.w * b.w;
        }
    }
    g += dtvL[r] * W_t[c];
    const float zv = 1.f / (1.f + __expf(-g));
    zn_s[r][c] = zv;
    z_slot[slot * H + c] = zv;                      // versioned publish (z)
    if (lastupL[r])                                 // final updater writes output
        z_out[(size_t)nodeL[r] * H + c] = zv;
    __syncthreads();                                // zn_s ready for phase C

    // ---- Phase C: publish h_slot[slot] (unconditional) ----
    {
        float h = 0.f;
        const float4* wh4 = (const float4*)(W_h + (size_t)c * H);
#pragma unroll
        for (int i = 0; i < 32; ++i) {
            const float4 a = wh4[i];
            const float4 zz = *(const float4*)&zn_s[r][4 * i];
            h += zz.x * a.x + zz.y * a.y + zz.z * a.z + zz.w * a.w;
        }
        h_slot[slot * H + c] = h + b_h[c];
    }

    // ---- release (unconditional) ----
    __syncthreads();
    if (tid == 0) {
        __threadfence();                            // agent-scope write visibility
        __hip_atomic_fetch_or(donebits, 1ull << e, __ATOMIC_RELEASE,
                              __HIP_MEMORY_SCOPE_AGENT);
    }
}

// ---------------------------------------------------------------------------
extern "C" void kernel_launch(void* const* d_in, const int* in_sizes, int n_in,
                              void* d_out, int out_size, void* d_ws, size_t ws_size,
                              hipStream_t stream)
{
    const int*   u        = (const int*)d_in[0];
    const int*   v        = (const int*)d_in[1];
    const float* t        = (const float*)d_in[2];
    const int*   k        = (const int*)d_in[3];
    const int*   u_others = (const int*)d_in[4];
    const int*   v_others = (const int*)d_in[5];
    const float* A        = (const float*)d_in[6];
    const float* S        = (const float*)d_in[7];
    const float* emb      = (const float*)d_in[8];
    const float* lastt    = (const float*)d_in[9];
    const float* W_S      = (const float*)d_in[10];
    const float* W_R      = (const float*)d_in[11];
    const float* W_t      = (const float*)d_in[12];
    const float* W_h      = (const float*)d_in[13];
    const float* b_h      = (const float*)d_in[14];
    const float* psi      = (const float*)d_in[15];
    const float* W_om     = (const float*)d_in[16];
    const float* b_om     = (const float*)d_in[17];
    (void)in_sizes; (void)n_in; (void)out_size; (void)ws_size;

    // Workspace layout kept from r16 (Mstat/dl/deg/dcnt slots now dead).
    float* wsf    = (float*)d_ws;
    float* h_tab  = wsf;                            // N*H
    float* d0     = h_tab + (size_t)N * H;          // N
    float* d1     = d0 + N;                         // N
    float* Mstat  = d1 + N;                         // 128*H (dead)
    float* dl_q   = Mstat + 128 * H;                // 128*MAXDIRTY (dead)
    float* z_slot = dl_q + 128 * MAXDIRTY;          // 128*H
    float* h_slot = z_slot + 128 * H;               // 128*H
    int*   deg    = (int*)(h_slot + 128 * H);       // 128 (dead)
    int*   dcnt   = deg + 128;                      // 128 (dead)
    int*   dl_s   = dcnt + 128;                     // 128*MAXDIRTY (dead)
    unsigned long long* donebits = (unsigned long long*)(dl_s + 128 * MAXDIRTY);

    float* out    = (float*)d_out;
    float* lamout = out;            // [64]
    float* svout  = out + NEV;      // [20]
    float* z_out  = out + NEV + SS; // [N*H]

    k_emb<<<N / RPB, 512, 0, stream>>>(emb, W_h, b_h, W_om, h_tab, z_out,
                                       d0, d1, donebits);
    k_parls<<<NEV + 1 + SS, 256, 0, stream>>>(u, v, t, k, u_others, v_others,
                                              lastt, emb, A, S, h_tab,
                                              W_S, W_R, W_t, W_h, b_h,
                                              psi, b_om, d0, d1,
                                              z_slot, h_slot, donebits,
                                              lamout, svout, z_out);
}

// Round 19
// 99.914 us; speedup vs baseline: 1.2299x; 1.1022x over previous
//
#include <hip/hip_runtime.h>
#include <math.h>

#define N 8192
#define H 128
#define NEV 64
#define SS 20
#define MAXD 512
#define MAXDIRTY 128
#define RPB 32
#define SPIN_GUARD (1 << 18)

// ---------------------------------------------------------------------------
// k_emb: h_tab = emb @ W_h.T + b_h ; z_out = emb copy ; d0/d1 rate dots.
// [byte-identical to round 18 — passed]
// ---------------------------------------------------------------------------
__global__ __launch_bounds__(512) void k_emb(
    const float* __restrict__ emb, const float* __restrict__ W_h,
    const float* __restrict__ b_h, const float* __restrict__ W_om,
    float* __restrict__ h_tab, float* __restrict__ z_out,
    float* __restrict__ d0, float* __restrict__ d1,
    unsigned long long* __restrict__ donebits)
{
    const int tid = threadIdx.x;
    const int c = tid & 127;
    const int s = tid >> 7;             // 0..3
    const int r0 = blockIdx.x * RPB;

    if (blockIdx.x == 0 && tid == 0) donebits[0] = 0ull;   // for k_parls

    __shared__ __align__(16) float z4[4 * 128];
    __shared__ float pr[8 * 128];

    float whr[32];
#pragma unroll
    for (int i = 0; i < 32; ++i) whr[i] = W_h[c * H + s * 32 + i];
    const float bh_c = b_h[c];

    const int lane = tid & 63;
    const int wid = tid >> 6;
    const int kof = (wid >= 4) ? 256 : 0;
    const float wk_l = W_om[kof + lane]      + W_om[kof + 128 + lane];
    const float wk_h = W_om[kof + 64 + lane] + W_om[kof + 192 + lane];

    for (int b = 0; b < RPB / 4; ++b) {
        const int rbase = r0 + b * 4;
        __syncthreads();
        const float zv = emb[(size_t)rbase * H + tid];
        z4[tid] = zv;
        z_out[(size_t)rbase * H + tid] = zv;
        __syncthreads();

#pragma unroll
        for (int rr = 0; rr < 4; ++rr) {
            float a = 0.f;
#pragma unroll
            for (int i4 = 0; i4 < 8; ++i4) {
                const float4 zz = *(const float4*)&z4[rr * 128 + s * 32 + i4 * 4];
                a += zz.x * whr[i4 * 4] + zz.y * whr[i4 * 4 + 1] +
                     zz.z * whr[i4 * 4 + 2] + zz.w * whr[i4 * 4 + 3];
            }
            pr[(s * 4 + rr) * 128 + c] = a;
        }
        {
            const int rr = wid & 3;
            float val = z4[rr * 128 + lane] * wk_l + z4[rr * 128 + 64 + lane] * wk_h;
#pragma unroll
            for (int off = 32; off > 0; off >>= 1) val += __shfl_xor(val, off);
            if (lane == 0) {
                if (wid < 4) d0[rbase + rr] = val;
                else         d1[rbase + rr] = val;
            }
        }
        __syncthreads();
        {
            const int rr = s;
            const float h = pr[(0 * 4 + rr) * 128 + c] + pr[(1 * 4 + rr) * 128 + c] +
                            pr[(2 * 4 + rr) * 128 + c] + pr[(3 * 4 + rr) * 128 + c] + bh_c;
            h_tab[(size_t)(rbase + rr) * H + c] = h;
        }
    }
}

// ---------------------------------------------------------------------------
// k_parls: r18 structure, 512 threads/block. Prep scan vectorized (float4,
// 4 iterations/row); phases A-C guarded to tid<256 (barriers top-level).
// ---------------------------------------------------------------------------
__global__ __launch_bounds__(512) void k_parls(
    const int* __restrict__ u, const int* __restrict__ v,
    const float* __restrict__ t, const int* __restrict__ kk,
    const int* __restrict__ u_o, const int* __restrict__ v_o,
    const float* __restrict__ lastt, const float* __restrict__ emb,
    const float* __restrict__ A, const float* __restrict__ S,
    const float* __restrict__ h_tab,
    const float* __restrict__ W_S, const float* __restrict__ W_R,
    const float* __restrict__ W_t, const float* __restrict__ W_h,
    const float* __restrict__ b_h,
    const float* __restrict__ psi, const float* __restrict__ b_om,
    const float* __restrict__ d0, const float* __restrict__ d1,
    float* __restrict__ z_slot, float* __restrict__ h_slot,
    unsigned long long* __restrict__ donebits,
    float* __restrict__ lamout, float* __restrict__ svout,
    float* __restrict__ z_out)
{
    const int bid = blockIdx.x;
    const int tid = threadIdx.x;

    if (bid >= NEV) {
        // ========== lam / survival roles (prior-dispatch reads only) =======
        if (bid == NEV) {
            if (tid < NEV) {
                const int b = tid;
                const int kv = kk[b];
                const float* dk = kv ? d1 : d0;
                const float g = 0.5f * (dk[u[b]] + dk[v[b]]) + b_om[kv];
                const float ps = psi[kv];
                const float x = fminf(75.f, fmaxf(-75.f, g / ps));
                lamout[b] = ps * log1pf(expf(x));
            }
        } else {
            const int s = bid - NEV - 1;
            if (tid < 64) {
                const int b = tid;
                const float p0 = psi[0], p1 = psi[1], bo0 = b_om[0], bo1 = b_om[1];
                const int vo = v_o[b * SS + s], uo = u_o[b * SS + s];
                float g, x;
                g = 0.5f * (d0[u[b]] + d0[vo]) + bo0; x = fminf(75.f, fmaxf(-75.f, g / p0));
                const float ru0 = p0 * log1pf(expf(x));
                g = 0.5f * (d1[u[b]] + d1[vo]) + bo1; x = fminf(75.f, fmaxf(-75.f, g / p1));
                const float ru1 = p1 * log1pf(expf(x));
                g = 0.5f * (d1[v[b]] + d1[uo]) + bo1; x = fminf(75.f, fmaxf(-75.f, g / p1));
                const float rv1 = p1 * log1pf(expf(x));
                float val = 2.f * (ru0 + ru1) + rv1;
#pragma unroll
                for (int off = 32; off > 0; off >>= 1) val += __shfl_xor(val, off);
                if (b == 0) svout[s] = val / (float)SS;
            }
        }
        return;
    }

    // ==================== par role with inline prep ========================
    const int e = bid;
    const int r = (tid >> 7) & 1;       // valid for tid<256 compute roles
    const int c = tid & 127;
    const int slot = 2 * e + r;

    __shared__ int   uL[NEV], vL[NEV];
    __shared__ int   nbr_i[MAXD];
    __shared__ float nbr_e[MAXD];
    __shared__ int   flagL[MAXD];
    __shared__ float rs[512];
    __shared__ float redm[512];
    __shared__ float msA[2][128];
    __shared__ int   dlsA[2][MAXDIRTY];
    __shared__ float dlqA[2][MAXDIRTY];
    __shared__ int   dcA[2], degA[2];
    __shared__ int   cntL, dcL;
    __shared__ float sumL;
    __shared__ __align__(16) float hs_s[2][128];
    __shared__ __align__(16) float zz_s[2][128];
    __shared__ __align__(16) float zn_s[2][128];
    __shared__ int   zdepL[2], lastupL[2], nodeL[2];
    __shared__ float dtvL[2];
    __shared__ unsigned long long need_s;

    if (tid < NEV)          uL[tid] = u[tid];
    else if (tid < 2 * NEV) vL[tid - NEV] = v[tid - NEV];
    __syncthreads();

    // ---- per-slot metadata from the event list (verbatim r18) ----
    if (tid < 2) {
        const int sl = 2 * e + tid;
        const int node = tid ? uL[e] : vL[e];    // slot 2e -> v[e], 2e+1 -> u[e]
        nodeL[tid] = node;
        int zd = -1;
        for (int j = 2 * e - 1; j >= 0; --j) {
            const int nj = (j & 1) ? uL[j >> 1] : vL[j >> 1];
            if (nj == node) { zd = j; break; }
        }
        zdepL[tid] = zd;
        int lu = 1;
        for (int j = sl + 1; j < 2 * NEV; ++j) {
            const int nj = (j & 1) ? uL[j >> 1] : vL[j >> 1];
            if (nj == node) { lu = 0; break; }
        }
        lastupL[tid] = lu;
        const int dtn = tid ? vL[e] : uL[e];     // crossed dt
        int pt = -1;
        for (int e2 = e - 1; e2 >= 0; --e2)
            if (uL[e2] == dtn || vL[e2] == dtn) { pt = e2; break; }
        const float lv = (pt >= 0) ? t[pt] : lastt[dtn];
        dtvL[tid] = t[e] - lv;
    }
    __syncthreads();

    // ---- inline prep: both slots, float4 scan, 512 threads ----
    for (int sl = 0; sl < 2; ++sl) {
        const int row = sl ? uL[e] : vL[e];
        const size_t base = (size_t)row * N;
        if (tid == 0) { cntL = 0; dcL = 0; }
        __syncthreads();

        // phase 1: vectorized adjacency scan, compact into LDS, sum exp(S)
        float lsum = 0.f;
        {
            const float4* A4 = (const float4*)(A + base);
            for (int j4 = tid; j4 < N / 4; j4 += 512) {
                const float4 a4 = A4[j4];
#pragma unroll
                for (int q = 0; q < 4; ++q) {
                    const float av = (q == 0) ? a4.x : (q == 1) ? a4.y
                                   : (q == 2) ? a4.z : a4.w;
                    if (av > 0.f) {
                        const int j = 4 * j4 + q;
                        const float ev = expf(S[base + j]);
                        lsum += ev;
                        const int p = atomicAdd(&cntL, 1);
                        if (p < MAXD) { nbr_i[p] = j; nbr_e[p] = ev; }
                    }
                }
            }
        }
        rs[tid] = lsum;
        __syncthreads();
        for (int off = 256; off > 0; off >>= 1) {
            if (tid < off) rs[tid] += rs[tid + off];
            __syncthreads();
        }
        if (tid == 0) { sumL = rs[0]; degA[sl] = cntL; }
        __syncthreads();

        const int d = min(cntL, MAXD);
        const float rinv = 1.f / (sumL + 1e-7f);

        // phase 1.5: per-neighbor latest-updater slot strictly before e
        for (int j0 = tid; j0 < d; j0 += 512) {
            const int j = nbr_i[j0];
            int dep = -1;
            for (int s2 = 2 * e - 1; s2 >= 0; --s2) {
                const int nj = (s2 & 1) ? uL[s2 >> 1] : vL[s2 >> 1];
                if (nj == j) { dep = s2; break; }
            }
            flagL[j0] = dep;                  // <0: static; >=0: dirty dep slot
        }
        __syncthreads();

        // phase 2: Mstat over static neighbors (h_tab, prior dispatch), 4-way
        {
            const int cc = tid & 127, quarter = tid >> 7;   // 0..3
            float m = -INFINITY;
            for (int j0 = quarter; j0 < d; j0 += 4) {
                if (flagL[j0] < 0)
                    m = fmaxf(m, nbr_e[j0] * rinv * h_tab[(size_t)nbr_i[j0] * H + cc]);
            }
            redm[tid] = m;
            __syncthreads();
            if (tid < 128)
                msA[sl][cc] = fmaxf(fmaxf(redm[cc], redm[128 + cc]),
                                    fmaxf(redm[256 + cc], redm[384 + cc]));
        }

        // phase 3: dirty list (latest-updater dep slots)
        for (int j0 = tid; j0 < d; j0 += 512) {
            const int dep = flagL[j0];
            if (dep >= 0) {
                const int p = atomicAdd(&dcL, 1);
                if (p < MAXDIRTY) { dlsA[sl][p] = dep; dlqA[sl][p] = nbr_e[j0] * rinv; }
            }
        }
        __syncthreads();
        if (tid == 0) dcA[sl] = dcL;
        __syncthreads();                      // nbr_i/e/flag reused next iter
    }

    // ---- build need-mask and spin (thread 0), then per-thread acquire ----
    if (tid == 0) {
        unsigned long long need = 0ull;
        for (int rr = 0; rr < 2; ++rr) {
            const int zd = zdepL[rr];
            if (zd >= 0) need |= 1ull << (zd >> 1);
            const int dn = min(dcA[rr], MAXDIRTY);
            for (int p = 0; p < dn; ++p)
                need |= 1ull << (dlsA[rr][p] >> 1);
        }
        need_s = need;
        if (need) {
            int guard = 0;
            while ((__hip_atomic_load(donebits, __ATOMIC_ACQUIRE,
                                      __HIP_MEMORY_SCOPE_AGENT) & need) != need) {
                __builtin_amdgcn_s_sleep(2);
                if (++guard > SPIN_GUARD) break;       // safety valve
            }
        }
    }
    __syncthreads();
    if (need_s) {   // per-thread acquire: invalidate stale cache lines on this CU
        unsigned long long db = __hip_atomic_load(donebits, __ATOMIC_ACQUIRE,
                                                  __HIP_MEMORY_SCOPE_AGENT);
        (void)db;
    }

    // ---- Phase A: hs (Mstat + dirty via h_slot) and z (versioned) ----
    if (tid < 256) {
        float m = msA[r][c];
        const int dn = min(dcA[r], MAXDIRTY);
        for (int p = 0; p < dn; ++p) {
            const int ds = dlsA[r][p];
            const float q = dlqA[r][p];
            m = fmaxf(m, q * h_slot[ds * H + c]);
        }
        hs_s[r][c] = (degA[r] > 0) ? 1.f / (1.f + __expf(-m)) : 0.f;
        const int zd = zdepL[r];
        zz_s[r][c] = (zd >= 0) ? z_slot[zd * H + c]
                               : emb[(size_t)nodeL[r] * H + c];
    }
    __syncthreads();

    // ---- Phase B: g = hs.W_S[c] + z.W_R[c] + dt*W_t[c]; sigmoid ----
    if (tid < 256) {
        float g = 0.f;
        const float4* ws4 = (const float4*)(W_S + (size_t)c * H);
        const float4* wr4 = (const float4*)(W_R + (size_t)c * H);
#pragma unroll
        for (int i = 0; i < 32; ++i) {
            const float4 a = ws4[i];
            const float4 b = wr4[i];
            const float4 hh = *(const float4*)&hs_s[r][4 * i];   // LDS broadcast
            const float4 zz = *(const float4*)&zz_s[r][4 * i];
            g += hh.x * a.x + hh.y * a.y + hh.z * a.z + hh.w * a.w +
                 zz.x * b.x + zz.y * b.y + zz.z * b.z + zz.w * b.w;
        }
        g += dtvL[r] * W_t[c];
        const float zv = 1.f / (1.f + __expf(-g));
        zn_s[r][c] = zv;
        z_slot[slot * H + c] = zv;                  // versioned publish (z)
        if (lastupL[r])                             // final updater writes output
            z_out[(size_t)nodeL[r] * H + c] = zv;
    }
    __syncthreads();                                // zn_s ready for phase C

    // ---- Phase C: publish h_slot[slot] (unconditional) ----
    if (tid < 256) {
        float h = 0.f;
        const float4* wh4 = (const float4*)(W_h + (size_t)c * H);
#pragma unroll
        for (int i = 0; i < 32; ++i) {
            const float4 a = wh4[i];
            const float4 zz = *(const float4*)&zn_s[r][4 * i];
            h += zz.x * a.x + zz.y * a.y + zz.z * a.z + zz.w * a.w;
        }
        h_slot[slot * H + c] = h + b_h[c];
    }

    // ---- release (unconditional) ----
    __syncthreads();
    if (tid == 0) {
        __threadfence();                            // agent-scope write visibility
        __hip_atomic_fetch_or(donebits, 1ull << e, __ATOMIC_RELEASE,
                              __HIP_MEMORY_SCOPE_AGENT);
    }
}

// ---------------------------------------------------------------------------
extern "C" void kernel_launch(void* const* d_in, const int* in_sizes, int n_in,
                              void* d_out, int out_size, void* d_ws, size_t ws_size,
                              hipStream_t stream)
{
    const int*   u        = (const int*)d_in[0];
    const int*   v        = (const int*)d_in[1];
    const float* t        = (const float*)d_in[2];
    const int*   k        = (const int*)d_in[3];
    const int*   u_others = (const int*)d_in[4];
    const int*   v_others = (const int*)d_in[5];
    const float* A        = (const float*)d_in[6];
    const float* S        = (const float*)d_in[7];
    const float* emb      = (const float*)d_in[8];
    const float* lastt    = (const float*)d_in[9];
    const float* W_S      = (const float*)d_in[10];
    const float* W_R      = (const float*)d_in[11];
    const float* W_t      = (const float*)d_in[12];
    const float* W_h      = (const float*)d_in[13];
    const float* b_h      = (const float*)d_in[14];
    const float* psi      = (const float*)d_in[15];
    const float* W_om     = (const float*)d_in[16];
    const float* b_om     = (const float*)d_in[17];
    (void)in_sizes; (void)n_in; (void)out_size; (void)ws_size;

    // Workspace layout kept from r16/r18.
    float* wsf    = (float*)d_ws;
    float* h_tab  = wsf;                            // N*H
    float* d0     = h_tab + (size_t)N * H;          // N
    float* d1     = d0 + N;                         // N
    float* Mstat  = d1 + N;                         // 128*H (dead)
    float* dl_q   = Mstat + 128 * H;                // 128*MAXDIRTY (dead)
    float* z_slot = dl_q + 128 * MAXDIRTY;          // 128*H
    float* h_slot = z_slot + 128 * H;               // 128*H
    int*   deg    = (int*)(h_slot + 128 * H);       // 128 (dead)
    int*   dcnt   = deg + 128;                      // 128 (dead)
    int*   dl_s   = dcnt + 128;                     // 128*MAXDIRTY (dead)
    unsigned long long* donebits = (unsigned long long*)(dl_s + 128 * MAXDIRTY);

    float* out    = (float*)d_out;
    float* lamout = out;            // [64]
    float* svout  = out + NEV;      // [20]
    float* z_out  = out + NEV + SS; // [N*H]

    k_emb<<<N / RPB, 512, 0, stream>>>(emb, W_h, b_h, W_om, h_tab, z_out,
                                       d0, d1, donebits);
    k_parls<<<NEV + 1 + SS, 512, 0, stream>>>(u, v, t, k, u_others, v_others,
                                              lastt, emb, A, S, h_tab,
                                              W_S, W_R, W_t, W_h, b_h,
                                              psi, b_om, d0, d1,
                                              z_slot, h_slot, donebits,
                                              lamout, svout, z_out);
}

// Round 20
// 94.321 us; speedup vs baseline: 1.3028x; 1.0593x over previous
//
#include <hip/hip_runtime.h>
#include <math.h>

#define N 8192
#define H 128
#define NEV 64
#define SS 20
#define MAXD 512
#define MAXDIRTY 128
#define RPB 16
#define SPIN_GUARD (1 << 18)

// ---------------------------------------------------------------------------
// k_emb: h_tab = emb @ W_h.T + b_h ; z_out = emb copy ; d0/d1 rate dots.
// [r19 logic; RPB 32->16: 512 blocks, serial depth halved]
// ---------------------------------------------------------------------------
__global__ __launch_bounds__(512) void k_emb(
    const float* __restrict__ emb, const float* __restrict__ W_h,
    const float* __restrict__ b_h, const float* __restrict__ W_om,
    float* __restrict__ h_tab, float* __restrict__ z_out,
    float* __restrict__ d0, float* __restrict__ d1,
    unsigned long long* __restrict__ donebits)
{
    const int tid = threadIdx.x;
    const int c = tid & 127;
    const int s = tid >> 7;             // 0..3
    const int r0 = blockIdx.x * RPB;

    if (blockIdx.x == 0 && tid == 0) donebits[0] = 0ull;   // for k_parls

    __shared__ __align__(16) float z4[4 * 128];
    __shared__ float pr[8 * 128];

    float whr[32];
#pragma unroll
    for (int i = 0; i < 32; ++i) whr[i] = W_h[c * H + s * 32 + i];
    const float bh_c = b_h[c];

    const int lane = tid & 63;
    const int wid = tid >> 6;
    const int kof = (wid >= 4) ? 256 : 0;
    const float wk_l = W_om[kof + lane]      + W_om[kof + 128 + lane];
    const float wk_h = W_om[kof + 64 + lane] + W_om[kof + 192 + lane];

    for (int b = 0; b < RPB / 4; ++b) {
        const int rbase = r0 + b * 4;
        __syncthreads();
        const float zv = emb[(size_t)rbase * H + tid];
        z4[tid] = zv;
        z_out[(size_t)rbase * H + tid] = zv;
        __syncthreads();

#pragma unroll
        for (int rr = 0; rr < 4; ++rr) {
            float a = 0.f;
#pragma unroll
            for (int i4 = 0; i4 < 8; ++i4) {
                const float4 zz = *(const float4*)&z4[rr * 128 + s * 32 + i4 * 4];
                a += zz.x * whr[i4 * 4] + zz.y * whr[i4 * 4 + 1] +
                     zz.z * whr[i4 * 4 + 2] + zz.w * whr[i4 * 4 + 3];
            }
            pr[(s * 4 + rr) * 128 + c] = a;
        }
        {
            const int rr = wid & 3;
            float val = z4[rr * 128 + lane] * wk_l + z4[rr * 128 + 64 + lane] * wk_h;
#pragma unroll
            for (int off = 32; off > 0; off >>= 1) val += __shfl_xor(val, off);
            if (lane == 0) {
                if (wid < 4) d0[rbase + rr] = val;
                else         d1[rbase + rr] = val;
            }
        }
        __syncthreads();
        {
            const int rr = s;
            const float h = pr[(0 * 4 + rr) * 128 + c] + pr[(1 * 4 + rr) * 128 + c] +
                            pr[(2 * 4 + rr) * 128 + c] + pr[(3 * 4 + rr) * 128 + c] + bh_c;
            h_tab[(size_t)(rbase + rr) * H + c] = h;
        }
    }
}

// ---------------------------------------------------------------------------
// k_parls: r19 structure; prep for BOTH slots runs concurrently (half=tid>>8
// owns one adjacency row) in a single pipeline pass — scan latencies and
// h_tab gather chains overlap, barrier count halved. Phases A-C and the
// donebits protocol verbatim r19 (passed).
// ---------------------------------------------------------------------------
__global__ __launch_bounds__(512) void k_parls(
    const int* __restrict__ u, const int* __restrict__ v,
    const float* __restrict__ t, const int* __restrict__ kk,
    const int* __restrict__ u_o, const int* __restrict__ v_o,
    const float* __restrict__ lastt, const float* __restrict__ emb,
    const float* __restrict__ A, const float* __restrict__ S,
    const float* __restrict__ h_tab,
    const float* __restrict__ W_S, const float* __restrict__ W_R,
    const float* __restrict__ W_t, const float* __restrict__ W_h,
    const float* __restrict__ b_h,
    const float* __restrict__ psi, const float* __restrict__ b_om,
    const float* __restrict__ d0, const float* __restrict__ d1,
    float* __restrict__ z_slot, float* __restrict__ h_slot,
    unsigned long long* __restrict__ donebits,
    float* __restrict__ lamout, float* __restrict__ svout,
    float* __restrict__ z_out)
{
    const int bid = blockIdx.x;
    const int tid = threadIdx.x;

    if (bid >= NEV) {
        // ========== lam / survival roles (prior-dispatch reads only) =======
        if (bid == NEV) {
            if (tid < NEV) {
                const int b = tid;
                const int kv = kk[b];
                const float* dk = kv ? d1 : d0;
                const float g = 0.5f * (dk[u[b]] + dk[v[b]]) + b_om[kv];
                const float ps = psi[kv];
                const float x = fminf(75.f, fmaxf(-75.f, g / ps));
                lamout[b] = ps * log1pf(expf(x));
            }
        } else {
            const int s = bid - NEV - 1;
            if (tid < 64) {
                const int b = tid;
                const float p0 = psi[0], p1 = psi[1], bo0 = b_om[0], bo1 = b_om[1];
                const int vo = v_o[b * SS + s], uo = u_o[b * SS + s];
                float g, x;
                g = 0.5f * (d0[u[b]] + d0[vo]) + bo0; x = fminf(75.f, fmaxf(-75.f, g / p0));
                const float ru0 = p0 * log1pf(expf(x));
                g = 0.5f * (d1[u[b]] + d1[vo]) + bo1; x = fminf(75.f, fmaxf(-75.f, g / p1));
                const float ru1 = p1 * log1pf(expf(x));
                g = 0.5f * (d1[v[b]] + d1[uo]) + bo1; x = fminf(75.f, fmaxf(-75.f, g / p1));
                const float rv1 = p1 * log1pf(expf(x));
                float val = 2.f * (ru0 + ru1) + rv1;
#pragma unroll
                for (int off = 32; off > 0; off >>= 1) val += __shfl_xor(val, off);
                if (b == 0) svout[s] = val / (float)SS;
            }
        }
        return;
    }

    // ==================== par role with fused dual-slot prep ===============
    const int e = bid;
    const int r = (tid >> 7) & 1;       // compute-role row (tid<256)
    const int c = tid & 127;
    const int slot = 2 * e + r;
    const int half = tid >> 8;          // prep role: 0 -> v-row, 1 -> u-row
    const int ht = tid & 255;           // thread id within half

    __shared__ int   uL[NEV], vL[NEV];
    __shared__ int   nbr2[2][MAXD];
    __shared__ float nbe2[2][MAXD];
    __shared__ int   flag2[2][MAXD];
    __shared__ float rs[512];
    __shared__ float redm[512];
    __shared__ float msA[2][128];
    __shared__ int   dlsA[2][MAXDIRTY];
    __shared__ float dlqA[2][MAXDIRTY];
    __shared__ int   dcA[2], degA[2], cntA[2];
    __shared__ float sumA[2];
    __shared__ __align__(16) float hs_s[2][128];
    __shared__ __align__(16) float zz_s[2][128];
    __shared__ __align__(16) float zn_s[2][128];
    __shared__ int   zdepL[2], lastupL[2], nodeL[2];
    __shared__ float dtvL[2];
    __shared__ unsigned long long need_s;

    if (tid < NEV)          uL[tid] = u[tid];
    else if (tid < 2 * NEV) vL[tid - NEV] = v[tid - NEV];
    if (tid < 2) { cntA[tid] = 0; dcA[tid] = 0; }
    __syncthreads();

    // ---- per-slot metadata from the event list (verbatim r19) ----
    if (tid < 2) {
        const int sl = 2 * e + tid;
        const int node = tid ? uL[e] : vL[e];    // slot 2e -> v[e], 2e+1 -> u[e]
        nodeL[tid] = node;
        int zd = -1;
        for (int j = 2 * e - 1; j >= 0; --j) {
            const int nj = (j & 1) ? uL[j >> 1] : vL[j >> 1];
            if (nj == node) { zd = j; break; }
        }
        zdepL[tid] = zd;
        int lu = 1;
        for (int j = sl + 1; j < 2 * NEV; ++j) {
            const int nj = (j & 1) ? uL[j >> 1] : vL[j >> 1];
            if (nj == node) { lu = 0; break; }
        }
        lastupL[tid] = lu;
        const int dtn = tid ? vL[e] : uL[e];     // crossed dt
        int pt = -1;
        for (int e2 = e - 1; e2 >= 0; --e2)
            if (uL[e2] == dtn || vL[e2] == dtn) { pt = e2; break; }
        const float lv = (pt >= 0) ? t[pt] : lastt[dtn];
        dtvL[tid] = t[e] - lv;
    }
    __syncthreads();

    // ---- fused prep: each half scans its own adjacency row ----
    {
        const int rowN = half ? uL[e] : vL[e];
        const size_t baseN = (size_t)rowN * N;

        // phase 1: vectorized scan, compact into LDS, sum exp(S)
        float lsum = 0.f;
        {
            const float4* A4 = (const float4*)(A + baseN);
            for (int j4 = ht; j4 < N / 4; j4 += 256) {
                const float4 a4 = A4[j4];
#pragma unroll
                for (int q = 0; q < 4; ++q) {
                    const float av = (q == 0) ? a4.x : (q == 1) ? a4.y
                                   : (q == 2) ? a4.z : a4.w;
                    if (av > 0.f) {
                        const int j = 4 * j4 + q;
                        const float ev = expf(S[baseN + j]);
                        lsum += ev;
                        const int p = atomicAdd(&cntA[half], 1);
                        if (p < MAXD) { nbr2[half][p] = j; nbe2[half][p] = ev; }
                    }
                }
            }
        }
        rs[tid] = lsum;
        __syncthreads();
        for (int off = 128; off > 0; off >>= 1) {       // per-half reduction
            if (ht < off) rs[tid] += rs[tid + off];
            __syncthreads();
        }
        if (ht == 0) { sumA[half] = rs[tid]; degA[half] = cntA[half]; }
        __syncthreads();

        const int dH = min(cntA[half], MAXD);
        const float rinvH = 1.f / (sumA[half] + 1e-7f);

        // phase 1.5: per-neighbor latest-updater slot strictly before e
        for (int j0 = ht; j0 < dH; j0 += 256) {
            const int j = nbr2[half][j0];
            int dep = -1;
            for (int s2 = 2 * e - 1; s2 >= 0; --s2) {
                const int nj = (s2 & 1) ? uL[s2 >> 1] : vL[s2 >> 1];
                if (nj == j) { dep = s2; break; }
            }
            flag2[half][j0] = dep;            // <0: static; >=0: dirty dep slot
        }
        __syncthreads();

        // phase 2: Mstat over static neighbors (h_tab, prior dispatch)
        {
            const int cc = ht & 127, pr2 = ht >> 7;      // 2-way per half
            float m = -INFINITY;
            for (int j0 = pr2; j0 < dH; j0 += 2) {
                if (flag2[half][j0] < 0)
                    m = fmaxf(m, nbe2[half][j0] * rinvH *
                              h_tab[(size_t)nbr2[half][j0] * H + cc]);
            }
            redm[tid] = m;
            __syncthreads();
            if (ht < 128)
                msA[half][cc] = fmaxf(redm[half * 256 + cc],
                                      redm[half * 256 + 128 + cc]);
        }

        // phase 3: dirty list (latest-updater dep slots)
        for (int j0 = ht; j0 < dH; j0 += 256) {
            const int dep = flag2[half][j0];
            if (dep >= 0) {
                const int p = atomicAdd(&dcA[half], 1);
                if (p < MAXDIRTY) { dlsA[half][p] = dep; dlqA[half][p] = nbe2[half][j0] * rinvH; }
            }
        }
        __syncthreads();
    }

    // ---- build need-mask and spin (thread 0), then per-thread acquire ----
    if (tid == 0) {
        unsigned long long need = 0ull;
        for (int rr = 0; rr < 2; ++rr) {
            const int zd = zdepL[rr];
            if (zd >= 0) need |= 1ull << (zd >> 1);
            const int dn = min(dcA[rr], MAXDIRTY);
            for (int p = 0; p < dn; ++p)
                need |= 1ull << (dlsA[rr][p] >> 1);
        }
        need_s = need;
        if (need) {
            int guard = 0;
            while ((__hip_atomic_load(donebits, __ATOMIC_ACQUIRE,
                                      __HIP_MEMORY_SCOPE_AGENT) & need) != need) {
                __builtin_amdgcn_s_sleep(2);
                if (++guard > SPIN_GUARD) break;       // safety valve
            }
        }
    }
    __syncthreads();
    if (need_s) {   // per-thread acquire: invalidate stale cache lines on this CU
        unsigned long long db = __hip_atomic_load(donebits, __ATOMIC_ACQUIRE,
                                                  __HIP_MEMORY_SCOPE_AGENT);
        (void)db;
    }

    // ---- Phase A: hs (Mstat + dirty via h_slot) and z (versioned) ----
    if (tid < 256) {
        float m = msA[r][c];
        const int dn = min(dcA[r], MAXDIRTY);
        for (int p = 0; p < dn; ++p) {
            const int ds = dlsA[r][p];
            const float q = dlqA[r][p];
            m = fmaxf(m, q * h_slot[ds * H + c]);
        }
        hs_s[r][c] = (degA[r] > 0) ? 1.f / (1.f + __expf(-m)) : 0.f;
        const int zd = zdepL[r];
        zz_s[r][c] = (zd >= 0) ? z_slot[zd * H + c]
                               : emb[(size_t)nodeL[r] * H + c];
    }
    __syncthreads();

    // ---- Phase B: g = hs.W_S[c] + z.W_R[c] + dt*W_t[c]; sigmoid ----
    if (tid < 256) {
        float g = 0.f;
        const float4* ws4 = (const float4*)(W_S + (size_t)c * H);
        const float4* wr4 = (const float4*)(W_R + (size_t)c * H);
#pragma unroll
        for (int i = 0; i < 32; ++i) {
            const float4 a = ws4[i];
            const float4 b = wr4[i];
            const float4 hh = *(const float4*)&hs_s[r][4 * i];   // LDS broadcast
            const float4 zz = *(const float4*)&zz_s[r][4 * i];
            g += hh.x * a.x + hh.y * a.y + hh.z * a.z + hh.w * a.w +
                 zz.x * b.x + zz.y * b.y + zz.z * b.z + zz.w * b.w;
        }
        g += dtvL[r] * W_t[c];
        const float zv = 1.f / (1.f + __expf(-g));
        zn_s[r][c] = zv;
        z_slot[slot * H + c] = zv;                  // versioned publish (z)
        if (lastupL[r])                             // final updater writes output
            z_out[(size_t)nodeL[r] * H + c] = zv;
    }
    __syncthreads();                                // zn_s ready for phase C

    // ---- Phase C: publish h_slot[slot] (unconditional) ----
    if (tid < 256) {
        float h = 0.f;
        const float4* wh4 = (const float4*)(W_h + (size_t)c * H);
#pragma unroll
        for (int i = 0; i < 32; ++i) {
            const float4 a = wh4[i];
            const float4 zz = *(const float4*)&zn_s[r][4 * i];
            h += zz.x * a.x + zz.y * a.y + zz.z * a.z + zz.w * a.w;
        }
        h_slot[slot * H + c] = h + b_h[c];
    }

    // ---- release (unconditional) ----
    __syncthreads();
    if (tid == 0) {
        __threadfence();                            // agent-scope write visibility
        __hip_atomic_fetch_or(donebits, 1ull << e, __ATOMIC_RELEASE,
                              __HIP_MEMORY_SCOPE_AGENT);
    }
}

// ---------------------------------------------------------------------------
extern "C" void kernel_launch(void* const* d_in, const int* in_sizes, int n_in,
                              void* d_out, int out_size, void* d_ws, size_t ws_size,
                              hipStream_t stream)
{
    const int*   u        = (const int*)d_in[0];
    const int*   v        = (const int*)d_in[1];
    const float* t        = (const float*)d_in[2];
    const int*   k        = (const int*)d_in[3];
    const int*   u_others = (const int*)d_in[4];
    const int*   v_others = (const int*)d_in[5];
    const float* A        = (const float*)d_in[6];
    const float* S        = (const float*)d_in[7];
    const float* emb      = (const float*)d_in[8];
    const float* lastt    = (const float*)d_in[9];
    const float* W_S      = (const float*)d_in[10];
    const float* W_R      = (const float*)d_in[11];
    const float* W_t      = (const float*)d_in[12];
    const float* W_h      = (const float*)d_in[13];
    const float* b_h      = (const float*)d_in[14];
    const float* psi      = (const float*)d_in[15];
    const float* W_om     = (const float*)d_in[16];
    const float* b_om     = (const float*)d_in[17];
    (void)in_sizes; (void)n_in; (void)out_size; (void)ws_size;

    // Workspace layout kept from r16/r18/r19.
    float* wsf    = (float*)d_ws;
    float* h_tab  = wsf;                            // N*H
    float* d0     = h_tab + (size_t)N * H;          // N
    float* d1     = d0 + N;                         // N
    float* Mstat  = d1 + N;                         // 128*H (dead)
    float* dl_q   = Mstat + 128 * H;                // 128*MAXDIRTY (dead)
    float* z_slot = dl_q + 128 * MAXDIRTY;          // 128*H
    float* h_slot = z_slot + 128 * H;               // 128*H
    int*   deg    = (int*)(h_slot + 128 * H);       // 128 (dead)
    int*   dcnt   = deg + 128;                      // 128 (dead)
    int*   dl_s   = dcnt + 128;                     // 128*MAXDIRTY (dead)
    unsigned long long* donebits = (unsigned long long*)(dl_s + 128 * MAXDIRTY);

    float* out    = (float*)d_out;
    float* lamout = out;            // [64]
    float* svout  = out + NEV;      // [20]
    float* z_out  = out + NEV + SS; // [N*H]

    k_emb<<<N / RPB, 512, 0, stream>>>(emb, W_h, b_h, W_om, h_tab, z_out,
                                       d0, d1, donebits);
    k_parls<<<NEV + 1 + SS, 512, 0, stream>>>(u, v, t, k, u_others, v_others,
                                              lastt, emb, A, S, h_tab,
                                              W_S, W_R, W_t, W_h, b_h,
                                              psi, b_om, d0, d1,
                                              z_slot, h_slot, donebits,
                                              lamout, svout, z_out);
}

// Round 22
// 87.056 us; speedup vs baseline: 1.4115x; 1.0834x over previous
//
#include <hip/hip_runtime.h>
#include <math.h>

#define N 8192
#define H 128
#define NEV 64
#define SS 20
#define MAXD 512
#define MAXDIRTY 128
#define RPB 8
#define SPIN_GUARD (1 << 18)

// ---------------------------------------------------------------------------
// k_emb: h_tab = emb @ W_h.T + b_h ; z_out = emb copy ; d0/d1 rate dots.
// FIX (latent since r1): pr must be [16][128] — indices (s*4+rr) span 0..15.
// The old [8][128] overflowed 4KB past the block's LDS allocation into
// co-resident blocks' z4/pr (cross-block race; r21's RPB=8 exposed it).
// ---------------------------------------------------------------------------
__global__ __launch_bounds__(512) void k_emb(
    const float* __restrict__ emb, const float* __restrict__ W_h,
    const float* __restrict__ b_h, const float* __restrict__ W_om,
    float* __restrict__ h_tab, float* __restrict__ z_out,
    float* __restrict__ d0, float* __restrict__ d1,
    unsigned long long* __restrict__ donebits)
{
    const int tid = threadIdx.x;
    const int c = tid & 127;
    const int s = tid >> 7;             // 0..3
    const int r0 = blockIdx.x * RPB;

    if (blockIdx.x == 0 && tid == 0) donebits[0] = 0ull;   // for k_parls

    __shared__ __align__(16) float z4[4 * 128];
    __shared__ float pr[16 * 128];      // [s*4+rr][c], s,rr in 0..3

    float whr[32];
#pragma unroll
    for (int i = 0; i < 32; ++i) whr[i] = W_h[c * H + s * 32 + i];
    const float bh_c = b_h[c];

    const int lane = tid & 63;
    const int wid = tid >> 6;
    const int kof = (wid >= 4) ? 256 : 0;
    const float wk_l = W_om[kof + lane]      + W_om[kof + 128 + lane];
    const float wk_h = W_om[kof + 64 + lane] + W_om[kof + 192 + lane];

    for (int b = 0; b < RPB / 4; ++b) {
        const int rbase = r0 + b * 4;
        __syncthreads();
        const float zv = emb[(size_t)rbase * H + tid];
        z4[tid] = zv;
        z_out[(size_t)rbase * H + tid] = zv;
        __syncthreads();

#pragma unroll
        for (int rr = 0; rr < 4; ++rr) {
            float a = 0.f;
#pragma unroll
            for (int i4 = 0; i4 < 8; ++i4) {
                const float4 zz = *(const float4*)&z4[rr * 128 + s * 32 + i4 * 4];
                a += zz.x * whr[i4 * 4] + zz.y * whr[i4 * 4 + 1] +
                     zz.z * whr[i4 * 4 + 2] + zz.w * whr[i4 * 4 + 3];
            }
            pr[(s * 4 + rr) * 128 + c] = a;
        }
        {
            const int rr = wid & 3;
            float val = z4[rr * 128 + lane] * wk_l + z4[rr * 128 + 64 + lane] * wk_h;
#pragma unroll
            for (int off = 32; off > 0; off >>= 1) val += __shfl_xor(val, off);
            if (lane == 0) {
                if (wid < 4) d0[rbase + rr] = val;
                else         d1[rbase + rr] = val;
            }
        }
        __syncthreads();
        {
            const int rr = s;
            const float h = pr[(0 * 4 + rr) * 128 + c] + pr[(1 * 4 + rr) * 128 + c] +
                            pr[(2 * 4 + rr) * 128 + c] + pr[(3 * 4 + rr) * 128 + c] + bh_c;
            h_tab[(size_t)(rbase + rr) * H + c] = h;
        }
    }
}

// ---------------------------------------------------------------------------
// k_parls: r21 structure (ballot metadata + fused dual-slot prep), verbatim.
// ---------------------------------------------------------------------------
__global__ __launch_bounds__(512) void k_parls(
    const int* __restrict__ u, const int* __restrict__ v,
    const float* __restrict__ t, const int* __restrict__ kk,
    const int* __restrict__ u_o, const int* __restrict__ v_o,
    const float* __restrict__ lastt, const float* __restrict__ emb,
    const float* __restrict__ A, const float* __restrict__ S,
    const float* __restrict__ h_tab,
    const float* __restrict__ W_S, const float* __restrict__ W_R,
    const float* __restrict__ W_t, const float* __restrict__ W_h,
    const float* __restrict__ b_h,
    const float* __restrict__ psi, const float* __restrict__ b_om,
    const float* __restrict__ d0, const float* __restrict__ d1,
    float* __restrict__ z_slot, float* __restrict__ h_slot,
    unsigned long long* __restrict__ donebits,
    float* __restrict__ lamout, float* __restrict__ svout,
    float* __restrict__ z_out)
{
    const int bid = blockIdx.x;
    const int tid = threadIdx.x;

    if (bid >= NEV) {
        // ========== lam / survival roles (prior-dispatch reads only) =======
        if (bid == NEV) {
            if (tid < NEV) {
                const int b = tid;
                const int kv = kk[b];
                const float* dk = kv ? d1 : d0;
                const float g = 0.5f * (dk[u[b]] + dk[v[b]]) + b_om[kv];
                const float ps = psi[kv];
                const float x = fminf(75.f, fmaxf(-75.f, g / ps));
                lamout[b] = ps * log1pf(expf(x));
            }
        } else {
            const int s = bid - NEV - 1;
            if (tid < 64) {
                const int b = tid;
                const float p0 = psi[0], p1 = psi[1], bo0 = b_om[0], bo1 = b_om[1];
                const int vo = v_o[b * SS + s], uo = u_o[b * SS + s];
                float g, x;
                g = 0.5f * (d0[u[b]] + d0[vo]) + bo0; x = fminf(75.f, fmaxf(-75.f, g / p0));
                const float ru0 = p0 * log1pf(expf(x));
                g = 0.5f * (d1[u[b]] + d1[vo]) + bo1; x = fminf(75.f, fmaxf(-75.f, g / p1));
                const float ru1 = p1 * log1pf(expf(x));
                g = 0.5f * (d1[v[b]] + d1[uo]) + bo1; x = fminf(75.f, fmaxf(-75.f, g / p1));
                const float rv1 = p1 * log1pf(expf(x));
                float val = 2.f * (ru0 + ru1) + rv1;
#pragma unroll
                for (int off = 32; off > 0; off >>= 1) val += __shfl_xor(val, off);
                if (b == 0) svout[s] = val / (float)SS;
            }
        }
        return;
    }

    // ==================== par role with fused dual-slot prep ===============
    const int e = bid;
    const int r = (tid >> 7) & 1;       // compute-role row (tid<256)
    const int c = tid & 127;
    const int slot = 2 * e + r;
    const int half = tid >> 8;          // prep role: 0 -> v-row, 1 -> u-row
    const int ht = tid & 255;           // thread id within half

    __shared__ int   uL[NEV], vL[NEV];
    __shared__ int   nbr2[2][MAXD];
    __shared__ float nbe2[2][MAXD];
    __shared__ int   flag2[2][MAXD];
    __shared__ float rs[512];
    __shared__ float redm[512];
    __shared__ float msA[2][128];
    __shared__ int   dlsA[2][MAXDIRTY];
    __shared__ float dlqA[2][MAXDIRTY];
    __shared__ int   dcA[2], degA[2], cntA[2];
    __shared__ float sumA[2];
    __shared__ __align__(16) float hs_s[2][128];
    __shared__ __align__(16) float zz_s[2][128];
    __shared__ __align__(16) float zn_s[2][128];
    __shared__ int   zdepL[2], lastupL[2], nodeL[2];
    __shared__ float dtvL[2];
    __shared__ unsigned long long maskN[4];
    __shared__ unsigned long long maskE[2];
    __shared__ unsigned long long need_s;

    if (tid < NEV)          uL[tid] = u[tid];
    else if (tid < 2 * NEV) vL[tid - NEV] = v[tid - NEV];
    if (tid < 2) { cntA[tid] = 0; dcA[tid] = 0; }
    __syncthreads();

    // ---- per-slot metadata via wave ballots (O(1)) ----
    if (tid < 256) {
        const int i  = tid >> 7;        // slot-in-event: 0 -> v-row, 1 -> u-row
        const int hj = tid & 127;       // candidate slot j
        const int lane = tid & 63;
        const int w  = tid >> 6;        // wave 0..3
        const int node = i ? uL[e] : vL[e];
        const int dtn  = i ? vL[e] : uL[e];
        const bool m1 = (((hj & 1) ? uL[hj >> 1] : vL[hj >> 1]) == node);
        const unsigned long long b1 = __ballot(m1);
        if (lane == 0) maskN[w] = b1;
        const bool m2 = (uL[lane] == dtn) || (vL[lane] == dtn);
        const unsigned long long b2 = __ballot(m2);
        if (lane == 0 && (w & 1) == 0) maskE[i] = b2;
    }
    __syncthreads();
    if (tid < 2) {
        const int i = tid;
        const int sl = 2 * e + i;
        const int dtn = i ? vL[e] : uL[e];
        nodeL[i] = i ? uL[e] : vL[e];
        const unsigned long long lo = maskN[2 * i], hi = maskN[2 * i + 1];
        auto msk = [](int n) -> unsigned long long {
            return (n >= 64) ? ~0ull : ((n <= 0) ? 0ull : ((1ull << n) - 1ull));
        };
        const unsigned long long loB = lo & msk(2 * e);
        const unsigned long long hiB = hi & msk(2 * e - 64);
        int zd = -1;
        if (hiB)      zd = 64 + (63 - __builtin_clzll(hiB));
        else if (loB) zd = 63 - __builtin_clzll(loB);
        zdepL[i] = zd;
        const unsigned long long loA = lo & ~msk(sl + 1);
        const unsigned long long hiA = hi & ~msk(sl + 1 - 64);
        lastupL[i] = ((loA | hiA) == 0ull) ? 1 : 0;
        const unsigned long long me = maskE[i] & msk(e);
        const int pt = me ? (63 - __builtin_clzll(me)) : -1;
        const float lv = (pt >= 0) ? t[pt] : lastt[dtn];
        dtvL[i] = t[e] - lv;
    }
    __syncthreads();

    // ---- fused prep: each half scans its own adjacency row ----
    {
        const int rowN = half ? uL[e] : vL[e];
        const size_t baseN = (size_t)rowN * N;

        // phase 1: vectorized scan, compact into LDS, sum exp(S)
        float lsum = 0.f;
        {
            const float4* A4 = (const float4*)(A + baseN);
            for (int j4 = ht; j4 < N / 4; j4 += 256) {
                const float4 a4 = A4[j4];
#pragma unroll
                for (int q = 0; q < 4; ++q) {
                    const float av = (q == 0) ? a4.x : (q == 1) ? a4.y
                                   : (q == 2) ? a4.z : a4.w;
                    if (av > 0.f) {
                        const int j = 4 * j4 + q;
                        const float ev = expf(S[baseN + j]);
                        lsum += ev;
                        const int p = atomicAdd(&cntA[half], 1);
                        if (p < MAXD) { nbr2[half][p] = j; nbe2[half][p] = ev; }
                    }
                }
            }
        }
        rs[tid] = lsum;
        __syncthreads();
        for (int off = 128; off > 0; off >>= 1) {       // per-half reduction
            if (ht < off) rs[tid] += rs[tid + off];
            __syncthreads();
        }
        if (ht == 0) { sumA[half] = rs[tid]; degA[half] = cntA[half]; }
        __syncthreads();

        const int dH = min(cntA[half], MAXD);
        const float rinvH = 1.f / (sumA[half] + 1e-7f);

        // phase 1.5: per-neighbor latest-updater slot strictly before e
        for (int j0 = ht; j0 < dH; j0 += 256) {
            const int j = nbr2[half][j0];
            int dep = -1;
            for (int s2 = 2 * e - 1; s2 >= 0; --s2) {
                const int nj = (s2 & 1) ? uL[s2 >> 1] : vL[s2 >> 1];
                if (nj == j) { dep = s2; break; }
            }
            flag2[half][j0] = dep;            // <0: static; >=0: dirty dep slot
        }
        __syncthreads();

        // phase 2: Mstat over static neighbors (h_tab, prior dispatch)
        {
            const int cc = ht & 127, pr2 = ht >> 7;      // 2-way per half
            float m = -INFINITY;
            for (int j0 = pr2; j0 < dH; j0 += 2) {
                if (flag2[half][j0] < 0)
                    m = fmaxf(m, nbe2[half][j0] * rinvH *
                              h_tab[(size_t)nbr2[half][j0] * H + cc]);
            }
            redm[tid] = m;
            __syncthreads();
            if (ht < 128)
                msA[half][cc] = fmaxf(redm[half * 256 + cc],
                                      redm[half * 256 + 128 + cc]);
        }

        // phase 3: dirty list (latest-updater dep slots)
        for (int j0 = ht; j0 < dH; j0 += 256) {
            const int dep = flag2[half][j0];
            if (dep >= 0) {
                const int p = atomicAdd(&dcA[half], 1);
                if (p < MAXDIRTY) { dlsA[half][p] = dep; dlqA[half][p] = nbe2[half][j0] * rinvH; }
            }
        }
        __syncthreads();
    }

    // ---- build need-mask and spin (thread 0), then per-thread acquire ----
    if (tid == 0) {
        unsigned long long need = 0ull;
        for (int rr = 0; rr < 2; ++rr) {
            const int zd = zdepL[rr];
            if (zd >= 0) need |= 1ull << (zd >> 1);
            const int dn = min(dcA[rr], MAXDIRTY);
            for (int p = 0; p < dn; ++p)
                need |= 1ull << (dlsA[rr][p] >> 1);
        }
        need_s = need;
        if (need) {
            int guard = 0;
            while ((__hip_atomic_load(donebits, __ATOMIC_ACQUIRE,
                                      __HIP_MEMORY_SCOPE_AGENT) & need) != need) {
                __builtin_amdgcn_s_sleep(2);
                if (++guard > SPIN_GUARD) break;       // safety valve
            }
        }
    }
    __syncthreads();
    if (need_s) {   // per-thread acquire: invalidate stale cache lines on this CU
        unsigned long long db = __hip_atomic_load(donebits, __ATOMIC_ACQUIRE,
                                                  __HIP_MEMORY_SCOPE_AGENT);
        (void)db;
    }

    // ---- Phase A: hs (Mstat + dirty via h_slot) and z (versioned) ----
    if (tid < 256) {
        float m = msA[r][c];
        const int dn = min(dcA[r], MAXDIRTY);
        for (int p = 0; p < dn; ++p) {
            const int ds = dlsA[r][p];
            const float q = dlqA[r][p];
            m = fmaxf(m, q * h_slot[ds * H + c]);
        }
        hs_s[r][c] = (degA[r] > 0) ? 1.f / (1.f + __expf(-m)) : 0.f;
        const int zd = zdepL[r];
        zz_s[r][c] = (zd >= 0) ? z_slot[zd * H + c]
                               : emb[(size_t)nodeL[r] * H + c];
    }
    __syncthreads();

    // ---- Phase B: g = hs.W_S[c] + z.W_R[c] + dt*W_t[c]; sigmoid ----
    if (tid < 256) {
        float g = 0.f;
        const float4* ws4 = (const float4*)(W_S + (size_t)c * H);
        const float4* wr4 = (const float4*)(W_R + (size_t)c * H);
#pragma unroll
        for (int i = 0; i < 32; ++i) {
            const float4 a = ws4[i];
            const float4 b = wr4[i];
            const float4 hh = *(const float4*)&hs_s[r][4 * i];   // LDS broadcast
            const float4 zz = *(const float4*)&zz_s[r][4 * i];
            g += hh.x * a.x + hh.y * a.y + hh.z * a.z + hh.w * a.w +
                 zz.x * b.x + zz.y * b.y + zz.z * b.z + zz.w * b.w;
        }
        g += dtvL[r] * W_t[c];
        const float zv = 1.f / (1.f + __expf(-g));
        zn_s[r][c] = zv;
        z_slot[slot * H + c] = zv;                  // versioned publish (z)
        if (lastupL[r])                             // final updater writes output
            z_out[(size_t)nodeL[r] * H + c] = zv;
    }
    __syncthreads();                                // zn_s ready for phase C

    // ---- Phase C: publish h_slot[slot] (unconditional) ----
    if (tid < 256) {
        float h = 0.f;
        const float4* wh4 = (const float4*)(W_h + (size_t)c * H);
#pragma unroll
        for (int i = 0; i < 32; ++i) {
            const float4 a = wh4[i];
            const float4 zz = *(const float4*)&zn_s[r][4 * i];
            h += zz.x * a.x + zz.y * a.y + zz.z * a.z + zz.w * a.w;
        }
        h_slot[slot * H + c] = h + b_h[c];
    }

    // ---- release (unconditional) ----
    __syncthreads();
    if (tid == 0) {
        __threadfence();                            // agent-scope write visibility
        __hip_atomic_fetch_or(donebits, 1ull << e, __ATOMIC_RELEASE,
                              __HIP_MEMORY_SCOPE_AGENT);
    }
}

// ---------------------------------------------------------------------------
extern "C" void kernel_launch(void* const* d_in, const int* in_sizes, int n_in,
                              void* d_out, int out_size, void* d_ws, size_t ws_size,
                              hipStream_t stream)
{
    const int*   u        = (const int*)d_in[0];
    const int*   v        = (const int*)d_in[1];
    const float* t        = (const float*)d_in[2];
    const int*   k        = (const int*)d_in[3];
    const int*   u_others = (const int*)d_in[4];
    const int*   v_others = (const int*)d_in[5];
    const float* A        = (const float*)d_in[6];
    const float* S        = (const float*)d_in[7];
    const float* emb      = (const float*)d_in[8];
    const float* lastt    = (const float*)d_in[9];
    const float* W_S      = (const float*)d_in[10];
    const float* W_R      = (const float*)d_in[11];
    const float* W_t      = (const float*)d_in[12];
    const float* W_h      = (const float*)d_in[13];
    const float* b_h      = (const float*)d_in[14];
    const float* psi      = (const float*)d_in[15];
    const float* W_om     = (const float*)d_in[16];
    const float* b_om     = (const float*)d_in[17];
    (void)in_sizes; (void)n_in; (void)out_size; (void)ws_size;

    // Workspace layout kept from r16-r21.
    float* wsf    = (float*)d_ws;
    float* h_tab  = wsf;                            // N*H
    float* d0     = h_tab + (size_t)N * H;          // N
    float* d1     = d0 + N;                         // N
    float* Mstat  = d1 + N;                         // 128*H (dead)
    float* dl_q   = Mstat + 128 * H;                // 128*MAXDIRTY (dead)
    float* z_slot = dl_q + 128 * MAXDIRTY;          // 128*H
    float* h_slot = z_slot + 128 * H;               // 128*H
    int*   deg    = (int*)(h_slot + 128 * H);       // 128 (dead)
    int*   dcnt   = deg + 128;                      // 128 (dead)
    int*   dl_s   = dcnt + 128;                     // 128*MAXDIRTY (dead)
    unsigned long long* donebits = (unsigned long long*)(dl_s + 128 * MAXDIRTY);

    float* out    = (float*)d_out;
    float* lamout = out;            // [64]
    float* svout  = out + NEV;      // [20]
    float* z_out  = out + NEV + SS; // [N*H]

    k_emb<<<N / RPB, 512, 0, stream>>>(emb, W_h, b_h, W_om, h_tab, z_out,
                                       d0, d1, donebits);
    k_parls<<<NEV + 1 + SS, 512, 0, stream>>>(u, v, t, k, u_others, v_others,
                                              lastt, emb, A, S, h_tab,
                                              W_S, W_R, W_t, W_h, b_h,
                                              psi, b_om, d0, d1,
                                              z_slot, h_slot, donebits,
                                              lamout, svout, z_out);
}